// Round 6
// baseline (524.693 us; speedup 1.0000x reference)
//
#include <hip/hip_runtime.h>

// Problem constants: E=800000 (=3125*256), N=50000, G=16, EMB=64.
#define EMB  64
#define NREP 256   // replica lines for per-graph global atomic spreading

typedef __attribute__((ext_vector_type(8))) short bf16x8;
typedef __attribute__((ext_vector_type(4))) float f32x4;
union BF8 { bf16x8 v; short s[8]; };

// float -> bf16 bits, round-to-nearest-even (finite inputs).
static __device__ __forceinline__ short f2bf(float f) {
    unsigned u = __float_as_uint(f);
    u += 0x7fffu + ((u >> 16) & 1u);
    return (short)(u >> 16);
}

// Software grid barrier (all blocks co-resident by construction: grid size is
// capped by hipOccupancyMaxActiveBlocksPerMultiprocessor * CU count on the
// host). Separate counter per barrier instance -> no sense reversal needed.
static __device__ __forceinline__ void grid_barrier(int* cnt, int nb) {
    __syncthreads();
    if (threadIdx.x == 0) {
        __threadfence();   // release: drain + make this block's writes visible
        __hip_atomic_fetch_add(cnt, 1, __ATOMIC_RELEASE, __HIP_MEMORY_SCOPE_AGENT);
        while (__hip_atomic_load(cnt, __ATOMIC_RELAXED, __HIP_MEMORY_SCOPE_AGENT) < nb)
            __builtin_amdgcn_s_sleep(2);
        __threadfence();   // acquire: invalidate stale cached lines
    }
    __syncthreads();
}

// ---------------------------------------------------------------------------
// ONE fused kernel (rounds 1-5 showed every extra "medium" dispatch in the
// graph costs ~230us regardless of its apparent work; fusing removes them).
// Phase 1: ecnt histogram (scattered atomics) + sorted-batch segment starts.
// Phase 2: R5's transposed-MFMA edge phase, grid-strided over 256-edge tiles:
//   A = W1^T (A-layout, 32 VGPRs, built once), B = X^T (lane = its edge's x
//   row, read once), D[m=o][n=edge] -> silu directly on D regs, quad
//   butterfly-reduce, scale by 1/ecnt[n], per-graph LDS bins, one 96-wide
//   replica-spread flush per block.
// Phase 3: block 0 reduces replicas, derives graph node counts from
//   boundaries, divides, expands 6 symmetric comps -> 9, writes out.
// ---------------------------------------------------------------------------
__global__ __launch_bounds__(256, 4) void fused_kernel(
    const float* __restrict__ dvec, const float* __restrict__ x_edge,
    const int*   __restrict__ eidx, const int* __restrict__ batch,
    const float* __restrict__ W1, const float* __restrict__ b1,
    const float* __restrict__ W2, const float* __restrict__ b2,
    int* __restrict__ ecnt, float* __restrict__ repsum,
    int* __restrict__ gStart, int* __restrict__ barcnt,
    float* __restrict__ out, int E, int N, int nb, int tiles)
{
    __shared__ float bins[96];
    __shared__ float sb1[64], sw2[64];
    __shared__ float sh[96];
    __shared__ int   gs[17];

    const int tid = threadIdx.x;
    if (tid < 96) bins[tid] = 0.f;
    if (tid < 64) { sb1[tid] = b1[tid]; sw2[tid] = W2[tid]; }

    const int lane = tid & 63, wave = tid >> 6;
    const int col  = lane & 15, quad = lane >> 4;

    // A fragments (independent of phase 1 -- build early, overlaps histogram):
    // A[m=mt*16+col][k=kt*32+quad*8+j] = W1[k][m]  (bf16 RNE)
    BF8 Af[4][2];
    #pragma unroll
    for (int mt = 0; mt < 4; ++mt)
        #pragma unroll
        for (int kt = 0; kt < 2; ++kt) {
            const float* wp = W1 + (kt * 32 + quad * 8) * 64 + mt * 16 + col;
            #pragma unroll
            for (int j = 0; j < 8; ++j) Af[mt][kt].s[j] = f2bf(wp[j * 64]);
        }

    // ---- Phase 1: histogram + boundaries (grid-stride) ----
    const int gt = blockIdx.x * 256 + tid, gsz = nb * 256;
    for (int t = gt; t < E; t += gsz) atomicAdd(&ecnt[eidx[t]], 1);
    for (int t = gt; t < N; t += gsz) {
        int g = batch[t];
        if (t == 0 || batch[t - 1] != g) gStart[g] = t;
    }
    grid_barrier(&barcnt[0], nb);

    // ---- Phase 2: edges ----
    const float NL2E = -1.442695040888963f;  // -log2(e)
    const float bb2  = b2[0];

    for (int tile = blockIdx.x; tile < tiles; tile += nb) {
        const long ebase = (long)tile * 256 + wave * 64;
        #pragma unroll 1
        for (int nt = 0; nt < 4; ++nt) {
            long e = ebase + nt * 16 + col;          // this lane's edge
            bool valid = (e < E);
            if (!valid) e = 0;

            int g = 0; float scale = 0.f;
            if (quad < 2) {
                int n = eidx[e];
                scale = 1.0f / (float)max(ecnt[n], 1);
                g = batch[n];
            }

            // B fragments: B[k][n=col] = x[e][k]
            const float* xp = x_edge + (size_t)e * EMB + quad * 8;
            f32x4 xa = *(const f32x4*)(xp);
            f32x4 xb = *(const f32x4*)(xp + 4);
            f32x4 xc = *(const f32x4*)(xp + 32);
            f32x4 xd = *(const f32x4*)(xp + 36);
            BF8 B0, B1;
            B0.s[0] = f2bf(xa.x); B0.s[1] = f2bf(xa.y); B0.s[2] = f2bf(xa.z); B0.s[3] = f2bf(xa.w);
            B0.s[4] = f2bf(xb.x); B0.s[5] = f2bf(xb.y); B0.s[6] = f2bf(xb.z); B0.s[7] = f2bf(xb.w);
            B1.s[0] = f2bf(xc.x); B1.s[1] = f2bf(xc.y); B1.s[2] = f2bf(xc.z); B1.s[3] = f2bf(xc.w);
            B1.s[4] = f2bf(xd.x); B1.s[5] = f2bf(xd.y); B1.s[6] = f2bf(xd.z); B1.s[7] = f2bf(xd.w);

            float d0 = dvec[3 * e + 0];
            float d1 = dvec[3 * e + 1];
            float d2 = dvec[3 * e + 2];
            float a[6] = { d0 * d0, d1 * d1, d2 * d2, d0 * d1, d0 * d2, d1 * d2 };
            float acc[6] = { 0.f, 0.f, 0.f, 0.f, 0.f, 0.f };

            #pragma unroll
            for (int mt = 0; mt < 4; ++mt) {
                f32x4 D = { 0.f, 0.f, 0.f, 0.f };
                D = __builtin_amdgcn_mfma_f32_16x16x32_bf16(Af[mt][0].v, B0.v, D, 0, 0, 0);
                D = __builtin_amdgcn_mfma_f32_16x16x32_bf16(Af[mt][1].v, B1.v, D, 0, 0, 0);
                #pragma unroll
                for (int r = 0; r < 4; ++r) {
                    int   o  = mt * 16 + quad * 4 + r;
                    float y  = D[r];
                    float b  = sb1[o];
                    float w2 = sw2[o];
                    #pragma unroll
                    for (int c = 0; c < 6; ++c) {
                        float z  = fmaf(a[c], y, b);
                        float ex = __builtin_amdgcn_exp2f(z * NL2E);
                        float rr = __builtin_amdgcn_rcpf(1.0f + ex);
                        acc[c]   = fmaf(w2, z * rr, acc[c]);
                    }
                }
            }

            #pragma unroll
            for (int c = 0; c < 6; ++c) {
                acc[c] += __shfl_xor(acc[c], 16, 64);
                acc[c] += __shfl_xor(acc[c], 32, 64);
            }

            if (valid && quad < 2) {
                #pragma unroll
                for (int j = 0; j < 3; ++j) {
                    int c = quad * 3 + j;
                    atomicAdd(&bins[g * 6 + c], (acc[c] + bb2) * scale);
                }
            }
        }
    }

    __syncthreads();
    if (tid < 96) {
        int rep = blockIdx.x & (NREP - 1);
        atomicAdd(repsum + (size_t)rep * 96 + tid, bins[tid]);
    }
    grid_barrier(&barcnt[16], nb);

    // ---- Phase 3: block 0 finalizes ----
    if (blockIdx.x == 0) {
        if (tid < 96) {
            float s = 0.f;
            #pragma unroll 8
            for (int r = 0; r < NREP; ++r) s += repsum[(size_t)r * 96 + tid];
            sh[tid] = s;
        }
        if (tid == 0) {
            gs[16] = N;
            for (int g = 15; g >= 0; --g) {
                unsigned v = (unsigned)gStart[g];   // 0xFFFFFFFF if graph empty
                gs[g] = (v > (unsigned)gs[g + 1]) ? gs[g + 1] : (int)v;
            }
        }
        __syncthreads();
        if (tid < 16) {
            int gN = gs[tid + 1] - gs[tid];
            float inv = 1.0f / fmaxf((float)gN, 1.0f);
            float m0 = sh[tid * 6 + 0] * inv;
            float m1 = sh[tid * 6 + 1] * inv;
            float m2 = sh[tid * 6 + 2] * inv;
            float m3 = sh[tid * 6 + 3] * inv;
            float m4 = sh[tid * 6 + 4] * inv;
            float m5 = sh[tid * 6 + 5] * inv;
            float* p = out + tid * 9;
            p[0] = m0; p[1] = m3; p[2] = m4;
            p[3] = m3; p[4] = m1; p[5] = m5;
            p[6] = m4; p[7] = m5; p[8] = m2;
        }
    }
}

// ---------------------------------------------------------------------------
extern "C" void kernel_launch(void* const* d_in, const int* in_sizes, int n_in,
                              void* d_out, int out_size, void* d_ws, size_t ws_size,
                              hipStream_t stream) {
    const float* dvec   = (const float*)d_in[0];   // [E,3]
    const float* x_edge = (const float*)d_in[1];   // [E,64]
    const int*   eidx   = (const int*)d_in[2];     // [E]
    const int*   batch  = (const int*)d_in[3];     // [N] sorted
    const float* W1     = (const float*)d_in[6];   // [64,64] (in,out)
    const float* b1     = (const float*)d_in[7];   // [64]
    const float* W2     = (const float*)d_in[8];   // [64,1]
    const float* b2     = (const float*)d_in[9];   // [1]

    int E = in_sizes[0] / 3;   // 800000
    int N = in_sizes[3];       // 50000

    // ws: ecnt[N] int | repsum[NREP*96] f | barcnt[32] int | gStart[16] int
    int*   ecnt   = (int*)d_ws;
    float* repsum = (float*)(ecnt + N);
    int*   barcnt = (int*)(repsum + (size_t)NREP * 96);
    int*   gStart = barcnt + 32;

    size_t zero_elems = (size_t)N + (size_t)NREP * 96 + 32;
    hipMemsetAsync(d_ws, 0, zero_elems * 4, stream);
    hipMemsetAsync(gStart, 0xFF, 16 * 4, stream);

    // Grid sized for guaranteed co-residency (software grid barrier).
    int occ = 0;
    hipOccupancyMaxActiveBlocksPerMultiprocessor(
        &occ, reinterpret_cast<const void*>(fused_kernel), 256, 0);
    if (occ < 1) occ = 1;
    int ncu = 0;
    hipDeviceGetAttribute(&ncu, hipDeviceAttributeMultiprocessorCount, 0);
    if (ncu <= 0) ncu = 256;

    int tiles = (E + 255) / 256;                      // 3125
    long maxb = (long)occ * ncu;
    int tpb = (int)((tiles + maxb - 1) / maxb);       // tiles per block
    int nb  = (tiles + tpb - 1) / tpb;                // balanced, <= maxb

    fused_kernel<<<nb, 256, 0, stream>>>(dvec, x_edge, eidx, batch,
                                         W1, b1, W2, b2,
                                         ecnt, repsum, gStart, barcnt,
                                         (float*)d_out, E, N, nb, tiles);
}